// Round 5
// baseline (1195.353 us; speedup 1.0000x reference)
//
#include <hip/hip_runtime.h>
#include <hip/hip_bf16.h>

#define S_LEN 1024
#define HID 7168
#define NH 128
#define DQ 1536
#define DKV 512
#define DH 128
#define DR 64

typedef __attribute__((ext_vector_type(8))) short bf16x8;
typedef __attribute__((ext_vector_type(4))) float f32x4;
typedef __attribute__((ext_vector_type(4))) float fl4;
typedef __attribute__((ext_vector_type(4))) unsigned short us4;
typedef __attribute__((ext_vector_type(8))) unsigned short us8;
typedef __attribute__((ext_vector_type(4))) unsigned int u32x4;

static __device__ __forceinline__ unsigned short f2bf(float f) {
  union { float f; unsigned int u; } v; v.f = f;
  unsigned int u = v.u;
  return (unsigned short)((u + 0x7fffu + ((u >> 16) & 1u)) >> 16);
}
static __device__ __forceinline__ float bf2f(unsigned short u) {
  union { unsigned int u; float f; } v; v.u = ((unsigned int)u) << 16;
  return v.f;
}
static __device__ __forceinline__ unsigned int cvtpk2(float lo, float hi) {
  unsigned int r;
  asm("v_cvt_pk_bf16_f32 %0, %1, %2" : "=v"(r) : "v"(lo), "v"(hi));
  return r;
}

// ---------------- fp32 -> bf16 conversion -------------------------------------
__global__ __launch_bounds__(256) void cvt_bf16_kernel(
    const float* __restrict__ in, unsigned short* __restrict__ out, int n8) {
  int i = blockIdx.x * 256 + threadIdx.x;
  int stride = gridDim.x * 256;
  for (; i < n8; i += stride) {
    fl4 a = ((const fl4*)in)[2 * i];
    fl4 b = ((const fl4*)in)[2 * i + 1];
    us8 u = { f2bf(a[0]), f2bf(a[1]), f2bf(a[2]), f2bf(a[3]),
              f2bf(b[0]), f2bf(b[1]), f2bf(b[2]), f2bf(b[3]) };
    ((us8*)out)[i] = u;
  }
}

// ---------------- bf16 GEMM (m97 structure) -----------------------------------
// OUTMODE 1: C = bf16((A@W^T + bias) * alpha), grid.z==1
// OUTMODE 2: fp32 partials per K-slice at Cv + z*zstride (split-K), no bias
// WFP32 1: W operand read as fp32 and converted in staging (v_cvt_pk_bf16_f32)
// grid.x may be PADDED to a multiple of 8 (XCD colocation of m-groups);
// blocks with n0 >= Ncl exit immediately (block-uniform).
template <int OUTMODE, int WFP32>
__global__ __launch_bounds__(256) void gemm_k(
    const unsigned short* __restrict__ A, int lda,
    const unsigned short* __restrict__ Wb16,
    const float* __restrict__ Wfa, const float* __restrict__ Wfb, int nsplit,
    int ldw,
    const float* __restrict__ bias,
    void* __restrict__ Cv, int ldc, size_t zstride,
    int Ncl, int ksl, float alpha)
{
  const int n0 = blockIdx.x * 128;
  if (n0 >= Ncl) return;                 // padded-grid early exit (block-uniform)

  __shared__ unsigned short As[128 * 64];
  __shared__ unsigned short Ws[128 * 64];
  const int t = threadIdx.x;
  const int l = t & 63, w = t >> 6;
  const int r15 = l & 15, g = l >> 4;
  const int wm = (w >> 1) * 64, wn = (w & 1) * 64;
  const int m0 = blockIdx.y * 128;
  const int kbase = blockIdx.z * ksl;
  const int srow = l >> 3;
  const int scol = (l & 7) * 8;

  f32x4 acc[4][4];
#pragma unroll
  for (int i = 0; i < 4; ++i)
#pragma unroll
    for (int j = 0; j < 4; ++j) acc[i][j] = (f32x4){0.f, 0.f, 0.f, 0.f};

  const unsigned short* Ab = A + (size_t)m0 * lda;
  const unsigned short* Wb = nullptr;
  const float* Wf = nullptr;
  if constexpr (WFP32) {
    Wf = (n0 < nsplit) ? Wfa + (size_t)n0 * ldw : Wfb + (size_t)(n0 - nsplit) * ldw;
  } else {
    Wb = Wb16 + (size_t)n0 * ldw;
  }

  for (int k0 = kbase; k0 < kbase + ksl; k0 += 64) {
    __syncthreads();
#pragma unroll
    for (int i = 0; i < 4; ++i) {
      int chunk = w * 4 + i;
      int row = chunk * 8 + srow;
      __builtin_amdgcn_global_load_lds(
          (const __attribute__((address_space(1))) void*)(Ab + (size_t)row * lda + k0 + scol),
          (__attribute__((address_space(3))) void*)(As + chunk * 512), 16, 0, 0);
      if constexpr (!WFP32) {
        __builtin_amdgcn_global_load_lds(
            (const __attribute__((address_space(1))) void*)(Wb + (size_t)row * ldw + k0 + scol),
            (__attribute__((address_space(3))) void*)(Ws + chunk * 512), 16, 0, 0);
      }
    }
    if constexpr (WFP32) {
#pragma unroll
      for (int i = 0; i < 4; ++i) {
        int c = t + 256 * i;
        int row = c >> 3, c8 = c & 7;
        const float* src = Wf + (size_t)row * ldw + k0 + c8 * 8;
        fl4 x = *(const fl4*)src;
        fl4 y = *(const fl4*)(src + 4);
        u32x4 p = { cvtpk2(x[0], x[1]), cvtpk2(x[2], x[3]),
                    cvtpk2(y[0], y[1]), cvtpk2(y[2], y[3]) };
        ((u32x4*)Ws)[c] = p;
      }
    }
    __syncthreads();
#pragma unroll
    for (int kk = 0; kk < 2; ++kk) {
      bf16x8 a[4], b[4];
#pragma unroll
      for (int mt = 0; mt < 4; ++mt)
        a[mt] = *reinterpret_cast<const bf16x8*>(&As[(wm + mt * 16 + r15) * 64 + kk * 32 + 8 * g]);
#pragma unroll
      for (int nt = 0; nt < 4; ++nt)
        b[nt] = *reinterpret_cast<const bf16x8*>(&Ws[(wn + nt * 16 + r15) * 64 + kk * 32 + 8 * g]);
#pragma unroll
      for (int mt = 0; mt < 4; ++mt)
#pragma unroll
        for (int nt = 0; nt < 4; ++nt)
          acc[mt][nt] = __builtin_amdgcn_mfma_f32_16x16x32_bf16(a[mt], b[nt], acc[mt][nt], 0, 0, 0);
    }
  }

  if constexpr (OUTMODE == 1) {
    float bv[4];
#pragma unroll
    for (int nt = 0; nt < 4; ++nt) {
      int col = n0 + wn + nt * 16 + r15;
      bv[nt] = (col < Ncl) ? bias[col] : 0.f;
    }
#pragma unroll
    for (int mt = 0; mt < 4; ++mt)
#pragma unroll
      for (int nt = 0; nt < 4; ++nt) {
        int col = n0 + wn + nt * 16 + r15;
        if (col < Ncl) {
#pragma unroll
          for (int r = 0; r < 4; ++r) {
            int row = m0 + wm + mt * 16 + g * 4 + r;
            ((unsigned short*)Cv)[(size_t)row * ldc + col] =
                f2bf((acc[mt][nt][r] + bv[nt]) * alpha);
          }
        }
      }
  } else {
    float* Cp = (float*)Cv + blockIdx.z * zstride;
#pragma unroll
    for (int mt = 0; mt < 4; ++mt)
#pragma unroll
      for (int nt = 0; nt < 4; ++nt) {
        int col = n0 + wn + nt * 16 + r15;
        if (col < Ncl) {
#pragma unroll
          for (int r = 0; r < 4; ++r) {
            int row = m0 + wm + mt * 16 + g * 4 + r;
            Cp[(size_t)row * ldc + col] = acc[mt][nt][r];
          }
        }
      }
  }
}

// ---------------- split-K reduction -------------------------------------------
__global__ __launch_bounds__(256) void reduce_f32_kernel(
    const float* __restrict__ pbuf, const float* __restrict__ bias,
    float* __restrict__ out, int ldo, int rowlen4, int nz, size_t zstride, int total4)
{
  int idx = blockIdx.x * 256 + threadIdx.x;
  if (idx >= total4) return;
  int r = idx / rowlen4, c4 = idx % rowlen4;
  fl4 acc = *(const fl4*)(bias + c4 * 4);
  for (int z = 0; z < nz; ++z)
    acc += *(const fl4*)(pbuf + z * zstride + (size_t)idx * 4);
  *(fl4*)(out + (size_t)r * ldo + c4 * 4) = acc;
}

__global__ __launch_bounds__(256) void reduce_bf16_kernel(
    const float* __restrict__ pbuf, const float* __restrict__ bias,
    unsigned short* __restrict__ out, int ldo, int rowlen4, int nz, size_t zstride, int total4)
{
  int idx = blockIdx.x * 256 + threadIdx.x;
  if (idx >= total4) return;
  int r = idx / rowlen4, c4 = idx % rowlen4;
  fl4 acc = *(const fl4*)(bias + c4 * 4);
  for (int z = 0; z < nz; ++z)
    acc += *(const fl4*)(pbuf + z * zstride + (size_t)idx * 4);
  us4 u = { f2bf(acc[0]), f2bf(acc[1]), f2bf(acc[2]), f2bf(acc[3]) };
  *(us4*)(out + (size_t)r * ldo + c4 * 4) = u;
}

// ---------------- rope tables + table-based rope ------------------------------
__global__ __launch_bounds__(256) void rope_table_kernel(float* __restrict__ ctab,
                                                         float* __restrict__ stab) {
  int idx = blockIdx.x * 256 + threadIdx.x;   // S_LEN*32 entries
  if (idx >= S_LEN * 32) return;
  int j = idx & 31, s = idx >> 5;
  float invf = expf(-0.28782313662425574f * (float)j);   // 10000^(-j/32)
  float ang = (float)s * invf;
  ctab[idx] = cosf(ang);
  stab[idx] = sinf(ang);
}

__global__ void rope_bf16_kernel(unsigned short* __restrict__ x, int nh, int lda, int total,
                                 const float* __restrict__ ctab,
                                 const float* __restrict__ stab) {
  int idx = blockIdx.x * 256 + threadIdx.x;
  if (idx >= total) return;
  int j = idx & 31;
  int rest = idx >> 5;
  int hh = rest % nh;
  int s = rest / nh;
  float c = ctab[s * 32 + j], sn = stab[s * 32 + j];
  size_t base = (size_t)s * lda + hh * 64;
  float x1 = bf2f(x[base + j]), x2 = bf2f(x[base + j + 32]);
  x[base + j]      = f2bf(x1 * c - x2 * sn);
  x[base + j + 32] = f2bf(x2 * c + x1 * sn);
}

// ---------------- V transpose -------------------------------------------------
__global__ __launch_bounds__(256) void vtrans_kernel(
    const unsigned short* __restrict__ kvb, unsigned short* __restrict__ vt) {
  __shared__ unsigned short tl[64][72];
  const int s0 = blockIdx.x * 64;
  const int c0 = blockIdx.y * 64;
  const int t = threadIdx.x;
  const int rr = t >> 3, cc = (t & 7) * 8;
  const int hbase = (c0 >> 7) * 256 + 128 + (c0 & 127);
#pragma unroll
  for (int i = 0; i < 2; ++i) {
    int r = rr + i * 32;
    *reinterpret_cast<bf16x8*>(&tl[r][cc]) =
        *reinterpret_cast<const bf16x8*>(kvb + (size_t)(s0 + r) * 32768 + hbase + cc);
  }
  __syncthreads();
#pragma unroll
  for (int i = 0; i < 2; ++i) {
    int vc = rr + i * 32;
    unsigned short tmp[8];
#pragma unroll
    for (int j = 0; j < 8; ++j) tmp[j] = tl[cc + j][vc];
    *reinterpret_cast<bf16x8*>(&vt[(size_t)(c0 + vc) * 1024 + s0 + cc]) =
        *reinterpret_cast<bf16x8*>(tmp);
  }
}

// ---------------- flash attention ---------------------------------------------
__global__ __launch_bounds__(256) void mla_attn_kernel(
    const unsigned short* __restrict__ qcat,
    const unsigned short* __restrict__ kvb,
    const unsigned short* __restrict__ kr,
    const unsigned short* __restrict__ vt,
    unsigned short* __restrict__ obuf)
{
  __shared__ unsigned short Klds[64][200];
  __shared__ unsigned short Vlds[128][72];
  __shared__ unsigned short Plds[4][16][72];

  const int t = threadIdx.x;
  const int l = t & 63, w = t >> 6;
  const int r15 = l & 15, g = l >> 4;
  const int bid = blockIdx.x;
  const int orig = (bid & 7) * 256 + (bid >> 3);   // 2048 % 8 == 0: bijective
  const int h = orig >> 4;
  const int q0 = (orig & 15) * 64;

  bf16x8 qf[6];
  const unsigned short* qrow = qcat + (size_t)(q0 + w * 16 + r15) * 24576;
#pragma unroll
  for (int kk = 0; kk < 4; ++kk)
    qf[kk] = *reinterpret_cast<const bf16x8*>(qrow + h * 128 + kk * 32 + 8 * g);
#pragma unroll
  for (int kk = 4; kk < 6; ++kk)
    qf[kk] = *reinterpret_cast<const bf16x8*>(qrow + 16384 + h * 64 + (kk - 4) * 32 + 8 * g);

  bf16x8 kreg[6], vreg[4];
  auto loadKV = [&](int kk0) {
#pragma unroll
    for (int i = 0; i < 6; ++i) {
      int c = t + 256 * i, row = c / 24, cb = c % 24;
      const unsigned short* src = (cb < 16)
          ? kvb + (size_t)(kk0 + row) * 32768 + h * 256 + cb * 8
          : kr + (size_t)(kk0 + row) * 2112 + (cb - 16) * 8;
      kreg[i] = *reinterpret_cast<const bf16x8*>(src);
    }
#pragma unroll
    for (int i = 0; i < 4; ++i) {
      int c = t + 256 * i, d = c >> 3, kb = c & 7;
      vreg[i] = *reinterpret_cast<const bf16x8*>(vt + ((size_t)h * 128 + d) * 1024 + kk0 + kb * 8);
    }
  };

  float m_r[4], l_r[4];
  f32x4 oacc[8];
#pragma unroll
  for (int r = 0; r < 4; ++r) { m_r[r] = -1e30f; l_r[r] = 0.f; }
#pragma unroll
  for (int d = 0; d < 8; ++d) oacc[d] = (f32x4){0.f, 0.f, 0.f, 0.f};

  loadKV(0);

  for (int kt = 0; kt < 16; ++kt) {
    __syncthreads();
#pragma unroll
    for (int i = 0; i < 6; ++i) {
      int c = t + 256 * i, row = c / 24, cb = c % 24;
      *reinterpret_cast<bf16x8*>(&Klds[row][cb * 8]) = kreg[i];
    }
#pragma unroll
    for (int i = 0; i < 4; ++i) {
      int c = t + 256 * i, d = c >> 3, kb = c & 7;
      *reinterpret_cast<bf16x8*>(&Vlds[d][kb * 8]) = vreg[i];
    }
    __syncthreads();
    if (kt < 15) loadKV((kt + 1) * 64);   // T14: loads land during compute

    // S = Q K^T
    f32x4 sacc[4];
#pragma unroll
    for (int nt = 0; nt < 4; ++nt) sacc[nt] = (f32x4){0.f, 0.f, 0.f, 0.f};
    __builtin_amdgcn_s_setprio(1);
#pragma unroll
    for (int nt = 0; nt < 4; ++nt)
#pragma unroll
      for (int kk = 0; kk < 6; ++kk) {
        bf16x8 b = *reinterpret_cast<const bf16x8*>(&Klds[nt * 16 + r15][kk * 32 + 8 * g]);
        sacc[nt] = __builtin_amdgcn_mfma_f32_16x16x32_bf16(qf[kk], b, sacc[nt], 0, 0, 0);
      }
    __builtin_amdgcn_s_setprio(0);

    // online softmax
    float sc[4], rsum[4];
#pragma unroll
    for (int r = 0; r < 4; ++r) {
      float mx = fmaxf(fmaxf(sacc[0][r], sacc[1][r]), fmaxf(sacc[2][r], sacc[3][r]));
      mx = fmaxf(mx, __shfl_xor(mx, 1));
      mx = fmaxf(mx, __shfl_xor(mx, 2));
      mx = fmaxf(mx, __shfl_xor(mx, 4));
      mx = fmaxf(mx, __shfl_xor(mx, 8));
      float mn = fmaxf(m_r[r], mx);
      sc[r] = __expf(m_r[r] - mn);
      m_r[r] = mn;
      rsum[r] = 0.f;
    }
#pragma unroll
    for (int nt = 0; nt < 4; ++nt)
#pragma unroll
      for (int r = 0; r < 4; ++r) {
        float p = __expf(sacc[nt][r] - m_r[r]);
        rsum[r] += p;
        Plds[w][g * 4 + r][nt * 16 + r15] = f2bf(p);
      }
#pragma unroll
    for (int r = 0; r < 4; ++r) {
      float s = rsum[r];
      s += __shfl_xor(s, 1);
      s += __shfl_xor(s, 2);
      s += __shfl_xor(s, 4);
      s += __shfl_xor(s, 8);
      l_r[r] = l_r[r] * sc[r] + s;
    }
#pragma unroll
    for (int d = 0; d < 8; ++d)
#pragma unroll
      for (int r = 0; r < 4; ++r) oacc[d][r] *= sc[r];

    // O += P V
    bf16x8 pa0 = *reinterpret_cast<const bf16x8*>(&Plds[w][r15][8 * g]);
    bf16x8 pa1 = *reinterpret_cast<const bf16x8*>(&Plds[w][r15][32 + 8 * g]);
    __builtin_amdgcn_s_setprio(1);
#pragma unroll
    for (int dt = 0; dt < 8; ++dt) {
      bf16x8 v0 = *reinterpret_cast<const bf16x8*>(&Vlds[dt * 16 + r15][8 * g]);
      bf16x8 v1 = *reinterpret_cast<const bf16x8*>(&Vlds[dt * 16 + r15][32 + 8 * g]);
      oacc[dt] = __builtin_amdgcn_mfma_f32_16x16x32_bf16(pa0, v0, oacc[dt], 0, 0, 0);
      oacc[dt] = __builtin_amdgcn_mfma_f32_16x16x32_bf16(pa1, v1, oacc[dt], 0, 0, 0);
    }
    __builtin_amdgcn_s_setprio(0);
  }

#pragma unroll
  for (int dt = 0; dt < 8; ++dt)
#pragma unroll
    for (int r = 0; r < 4; ++r) {
      int row = q0 + w * 16 + g * 4 + r;
      int col = h * DH + dt * 16 + r15;
      obuf[(size_t)row * 16384 + col] = f2bf(oacc[dt][r] / l_r[r]);
    }
}

// ------------------------------------------------------------------------------
extern "C" void kernel_launch(void* const* d_in, const int* in_sizes, int n_in,
                              void* d_out, int out_size, void* d_ws, size_t ws_size,
                              hipStream_t stream) {
  const float* h    = (const float*)d_in[0];
  const float* Wdq  = (const float*)d_in[1];
  const float* bdq  = (const float*)d_in[2];
  const float* Wdkv = (const float*)d_in[3];
  const float* bdkv = (const float*)d_in[4];
  const float* Wuq  = (const float*)d_in[5];
  const float* buq  = (const float*)d_in[6];
  const float* Wukv = (const float*)d_in[7];
  const float* bukv = (const float*)d_in[8];
  const float* Wrq  = (const float*)d_in[9];
  const float* brq  = (const float*)d_in[10];
  const float* Wrk  = (const float*)d_in[11];
  const float* brk  = (const float*)d_in[12];
  const float* Wo   = (const float*)d_in[13];
  const float* bo   = (const float*)d_in[14];
  float* out = (float*)d_out;

  char* ws = (char*)d_ws;
  size_t off = 0;
  auto alloc = [&](size_t bytes) {
    char* p = ws + off;
    off += (bytes + 255) & ~(size_t)255;
    return p;
  };
  unsigned short* hb    = (unsigned short*)alloc((size_t)1024 * 7168 * 2);
  unsigned short* W1cat = (unsigned short*)alloc((size_t)2176 * 7168 * 2);
  float*          b1cat = (float*)alloc(2176 * 4);
  unsigned short* ccat  = (unsigned short*)alloc((size_t)1024 * 2112 * 2);
  float*          b2cat = (float*)alloc(24576 * 4);
  unsigned short* qcat  = (unsigned short*)alloc((size_t)1024 * 24576 * 2);
  unsigned short* kvbb  = (unsigned short*)alloc((size_t)1024 * 32768 * 2);
  unsigned short* vt    = (unsigned short*)alloc((size_t)16384 * 1024 * 2);
  unsigned short* obuf  = (unsigned short*)alloc((size_t)1024 * 16384 * 2);
  float*          ctab  = (float*)alloc((size_t)S_LEN * 32 * 4);
  float*          stab  = (float*)alloc((size_t)S_LEN * 32 * 4);
  // G1 split-K partials alias not-yet-written qcat (34.6 MB < 50.3 MB)
  float* pbufG1 = (float*)qcat;
  // G4 split-K partials alias qcat+kvbb (exactly 117.44 MB), dead after attention
  float* pbufG4 = (float*)qcat;

  auto cvt = [&](const float* in, unsigned short* outp, size_t n) {
    int n8 = (int)(n / 8);
    int blocks = (n8 + 255) / 256;
    if (blocks > 2048) blocks = 2048;
    cvt_bf16_kernel<<<blocks, 256, 0, stream>>>(in, outp, n8);
  };

  // --- conversions kept only for h and the small concatenated W1 ---
  cvt(h,    hb,    (size_t)1024 * 7168);
  cvt(Wdq,  W1cat, (size_t)1536 * 7168);
  cvt(Wdkv, W1cat + (size_t)1536 * 7168, (size_t)512 * 7168);
  cvt(Wrk,  W1cat + (size_t)2048 * 7168, (size_t)64 * 7168);
  hipMemsetAsync(W1cat + (size_t)2112 * 7168, 0, (size_t)64 * 7168 * 2, stream);
  hipMemcpyAsync(b1cat,        bdq,  1536 * 4, hipMemcpyDeviceToDevice, stream);
  hipMemcpyAsync(b1cat + 1536, bdkv, 512 * 4,  hipMemcpyDeviceToDevice, stream);
  hipMemcpyAsync(b1cat + 2048, brk,  64 * 4,   hipMemcpyDeviceToDevice, stream);
  hipMemsetAsync(b1cat + 2112, 0, 64 * 4, stream);
  hipMemcpyAsync(b2cat,         buq, 16384 * 4, hipMemcpyDeviceToDevice, stream);
  hipMemcpyAsync(b2cat + 16384, brq, 8192 * 4,  hipMemcpyDeviceToDevice, stream);
  rope_table_kernel<<<(S_LEN * 32 + 255) / 256, 256, 0, stream>>>(ctab, stab);

  const float scale = 0.07216878364870323f;   // 1/sqrt(192)
  const int BIGN = 1 << 30;
  dim3 blk(256);

  // G1 (split-K=4, bf16 W): partials = h @ W1cat^T.  grid.x padded 17->24 (XCD colocation)
  gemm_k<2, 0><<<dim3(24, 8, 4), blk, 0, stream>>>(
      hb, 7168, W1cat, nullptr, nullptr, BIGN, 7168, nullptr,
      pbufG1, 2112, (size_t)1024 * 2112, 2112, 1792, 1.0f);
  reduce_bf16_kernel<<<2112, blk, 0, stream>>>(pbufG1, b1cat, ccat, 2112, 528, 4,
                                               (size_t)1024 * 2112, 1024 * 2112 / 4);
  rope_bf16_kernel<<<(1024 * 32 + 255) / 256, blk, 0, stream>>>(ccat + 2048, 1, 2112, 1024 * 32, ctab, stab);

  // G2 (fp32 W direct): [q_c | q_r] = (c_q @ [Wuq;Wrq]^T + b2cat) * scale
  gemm_k<1, 1><<<dim3(192, 8, 1), blk, 0, stream>>>(
      ccat, 2112, nullptr, Wuq, Wrq, 16384, 1536, b2cat,
      qcat, 24576, 0, 24576, 1536, scale);
  rope_bf16_kernel<<<(1024 * 128 * 32 + 255) / 256, blk, 0, stream>>>(qcat + 16384, 128, 24576, 1024 * 128 * 32, ctab, stab);

  // G3 (fp32 W direct): kv = c_kv @ Wukv^T + bukv
  gemm_k<1, 1><<<dim3(256, 8, 1), blk, 0, stream>>>(
      ccat + 1536, 2112, nullptr, Wukv, Wukv, BIGN, 512, bukv,
      kvbb, 32768, 0, 32768, 512, 1.0f);
  vtrans_kernel<<<dim3(16, 256), blk, 0, stream>>>(kvbb, vt);
  mla_attn_kernel<<<dim3(2048), blk, 0, stream>>>(qcat, kvbb, ccat + 2048, vt, obuf);

  // G4 (split-K=8, fp32 W direct): out = obuf @ Wo^T + bo, two N-halves.
  // grid.x padded 28->32 so the 8 m-blocks of each n-tile share one XCD's L2.
  for (int hn = 0; hn < 2; ++hn) {
    const float* Woh = Wo + (size_t)hn * 3584 * 16384;
    gemm_k<2, 1><<<dim3(32, 8, 8), blk, 0, stream>>>(
        obuf, 16384, nullptr, Woh, Woh, BIGN, 16384, nullptr,
        pbufG4, 3584, (size_t)1024 * 3584, 3584, 2048, 1.0f);
    reduce_f32_kernel<<<3584, blk, 0, stream>>>(pbufG4, bo + hn * 3584, out + hn * 3584,
                                                7168, 896, 8, (size_t)1024 * 3584, 1024 * 3584 / 4);
  }
}

// Round 6
// 1135.037 us; speedup vs baseline: 1.0531x; 1.0531x over previous
//
#include <hip/hip_runtime.h>
#include <hip/hip_bf16.h>

#define S_LEN 1024
#define HID 7168
#define NH 128
#define DQ 1536
#define DKV 512
#define DH 128
#define DR 64

typedef __attribute__((ext_vector_type(8))) short bf16x8;
typedef __attribute__((ext_vector_type(4))) float f32x4;
typedef __attribute__((ext_vector_type(4))) float fl4;
typedef __attribute__((ext_vector_type(4))) unsigned short us4;
typedef __attribute__((ext_vector_type(8))) unsigned short us8;
typedef __attribute__((ext_vector_type(4))) unsigned int u32x4;

static __device__ __forceinline__ unsigned short f2bf(float f) {
  union { float f; unsigned int u; } v; v.f = f;
  unsigned int u = v.u;
  return (unsigned short)((u + 0x7fffu + ((u >> 16) & 1u)) >> 16);
}
static __device__ __forceinline__ float bf2f(unsigned short u) {
  union { unsigned int u; float f; } v; v.u = ((unsigned int)u) << 16;
  return v.f;
}
static __device__ __forceinline__ unsigned int cvtpk2(float lo, float hi) {
  unsigned int r;
  asm("v_cvt_pk_bf16_f32 %0, %1, %2" : "=v"(r) : "v"(lo), "v"(hi));
  return r;
}

// ---------------- fp32 -> bf16 conversion -------------------------------------
__global__ __launch_bounds__(256) void cvt_bf16_kernel(
    const float* __restrict__ in, unsigned short* __restrict__ out, int n8) {
  int i = blockIdx.x * 256 + threadIdx.x;
  int stride = gridDim.x * 256;
  for (; i < n8; i += stride) {
    fl4 a = ((const fl4*)in)[2 * i];
    fl4 b = ((const fl4*)in)[2 * i + 1];
    us8 u = { f2bf(a[0]), f2bf(a[1]), f2bf(a[2]), f2bf(a[3]),
              f2bf(b[0]), f2bf(b[1]), f2bf(b[2]), f2bf(b[3]) };
    ((us8*)out)[i] = u;
  }
}

// ---------------- bf16 GEMM (m97 structure + T14 W-prefetch) ------------------
// OUTMODE 1: C = bf16((A@W^T + bias) * alpha), grid.z==1
// OUTMODE 2: fp32 partials per K-slice at Cv + z*zstride (split-K), no bias
// WFP32 1: W read as fp32, prefetched to regs one K-step ahead, converted with
//          v_cvt_pk_bf16_f32 during staging.
// grid.x may be PADDED to a multiple of 8 (XCD colocation of m-groups).
template <int OUTMODE, int WFP32>
__global__ __launch_bounds__(256) void gemm_k(
    const unsigned short* __restrict__ A, int lda,
    const unsigned short* __restrict__ Wb16,
    const float* __restrict__ Wfa, const float* __restrict__ Wfb, int nsplit,
    int ldw,
    const float* __restrict__ bias,
    void* __restrict__ Cv, int ldc, size_t zstride,
    int Ncl, int ksl, float alpha)
{
  const int n0 = blockIdx.x * 128;
  if (n0 >= Ncl) return;                 // padded-grid early exit (block-uniform)

  __shared__ unsigned short As[128 * 64];
  __shared__ unsigned short Ws[128 * 64];
  const int t = threadIdx.x;
  const int l = t & 63, w = t >> 6;
  const int r15 = l & 15, g = l >> 4;
  const int wm = (w >> 1) * 64, wn = (w & 1) * 64;
  const int m0 = blockIdx.y * 128;
  const int kbase = blockIdx.z * ksl;
  const int srow = l >> 3;
  const int scol = (l & 7) * 8;

  f32x4 acc[4][4];
#pragma unroll
  for (int i = 0; i < 4; ++i)
#pragma unroll
    for (int j = 0; j < 4; ++j) acc[i][j] = (f32x4){0.f, 0.f, 0.f, 0.f};

  const unsigned short* Ab = A + (size_t)m0 * lda;
  const unsigned short* Wb = nullptr;
  const float* Wf = nullptr;
  if constexpr (WFP32) {
    Wf = (n0 < nsplit) ? Wfa + (size_t)n0 * ldw : Wfb + (size_t)(n0 - nsplit) * ldw;
  } else {
    Wb = Wb16 + (size_t)n0 * ldw;
  }

  fl4 wx[4], wy[4];                      // W prefetch regs (static indexing only)
  auto issueW = [&](int k0) {
#pragma unroll
    for (int i = 0; i < 4; ++i) {
      int c = t + 256 * i;
      const float* src = Wf + (size_t)(c >> 3) * ldw + k0 + (c & 7) * 8;
      wx[i] = *(const fl4*)src;
      wy[i] = *(const fl4*)(src + 4);
    }
  };

  if constexpr (WFP32) issueW(kbase);
  const int kend = kbase + ksl;

  for (int k0 = kbase; k0 < kend; k0 += 64) {
    __syncthreads();                     // drains prev MFMA; W(k) regs arrive here
    // A staging (async, flies under the cvt VALU work)
#pragma unroll
    for (int i = 0; i < 4; ++i) {
      int chunk = w * 4 + i;
      int row = chunk * 8 + srow;
      __builtin_amdgcn_global_load_lds(
          (const __attribute__((address_space(1))) void*)(Ab + (size_t)row * lda + k0 + scol),
          (__attribute__((address_space(3))) void*)(As + chunk * 512), 16, 0, 0);
      if constexpr (!WFP32) {
        __builtin_amdgcn_global_load_lds(
            (const __attribute__((address_space(1))) void*)(Wb + (size_t)row * ldw + k0 + scol),
            (__attribute__((address_space(3))) void*)(Ws + chunk * 512), 16, 0, 0);
      }
    }
    if constexpr (WFP32) {
      // convert prefetched regs -> LDS
#pragma unroll
      for (int i = 0; i < 4; ++i) {
        int c = t + 256 * i;
        u32x4 p = { cvtpk2(wx[i][0], wx[i][1]), cvtpk2(wx[i][2], wx[i][3]),
                    cvtpk2(wy[i][0], wy[i][1]), cvtpk2(wy[i][2], wy[i][3]) };
        ((u32x4*)Ws)[c] = p;
      }
    }
    __syncthreads();                     // drains A glds (vmcnt0) + ds_writes
    if constexpr (WFP32) {
      if (k0 + 64 < kend) issueW(k0 + 64);   // T14: next W loads fly over MFMA
    }
#pragma unroll
    for (int kk = 0; kk < 2; ++kk) {
      bf16x8 a[4], b[4];
#pragma unroll
      for (int mt = 0; mt < 4; ++mt)
        a[mt] = *reinterpret_cast<const bf16x8*>(&As[(wm + mt * 16 + r15) * 64 + kk * 32 + 8 * g]);
#pragma unroll
      for (int nt = 0; nt < 4; ++nt)
        b[nt] = *reinterpret_cast<const bf16x8*>(&Ws[(wn + nt * 16 + r15) * 64 + kk * 32 + 8 * g]);
#pragma unroll
      for (int mt = 0; mt < 4; ++mt)
#pragma unroll
        for (int nt = 0; nt < 4; ++nt)
          acc[mt][nt] = __builtin_amdgcn_mfma_f32_16x16x32_bf16(a[mt], b[nt], acc[mt][nt], 0, 0, 0);
    }
  }

  if constexpr (OUTMODE == 1) {
    float bv[4];
#pragma unroll
    for (int nt = 0; nt < 4; ++nt) {
      int col = n0 + wn + nt * 16 + r15;
      bv[nt] = (col < Ncl) ? bias[col] : 0.f;
    }
#pragma unroll
    for (int mt = 0; mt < 4; ++mt)
#pragma unroll
      for (int nt = 0; nt < 4; ++nt) {
        int col = n0 + wn + nt * 16 + r15;
        if (col < Ncl) {
#pragma unroll
          for (int r = 0; r < 4; ++r) {
            int row = m0 + wm + mt * 16 + g * 4 + r;
            ((unsigned short*)Cv)[(size_t)row * ldc + col] =
                f2bf((acc[mt][nt][r] + bv[nt]) * alpha);
          }
        }
      }
  } else {
    float* Cp = (float*)Cv + blockIdx.z * zstride;
#pragma unroll
    for (int mt = 0; mt < 4; ++mt)
#pragma unroll
      for (int nt = 0; nt < 4; ++nt) {
        int col = n0 + wn + nt * 16 + r15;
        if (col < Ncl) {
#pragma unroll
          for (int r = 0; r < 4; ++r) {
            int row = m0 + wm + mt * 16 + g * 4 + r;
            Cp[(size_t)row * ldc + col] = acc[mt][nt][r];
          }
        }
      }
  }
}

// ---------------- split-K reduction -------------------------------------------
__global__ __launch_bounds__(256) void reduce_f32_kernel(
    const float* __restrict__ pbuf, const float* __restrict__ bias,
    float* __restrict__ out, int ldo, int rowlen4, int nz, size_t zstride, int total4)
{
  int idx = blockIdx.x * 256 + threadIdx.x;
  if (idx >= total4) return;
  int r = idx / rowlen4, c4 = idx % rowlen4;
  fl4 acc = *(const fl4*)(bias + c4 * 4);
  for (int z = 0; z < nz; ++z)
    acc += *(const fl4*)(pbuf + z * zstride + (size_t)idx * 4);
  *(fl4*)(out + (size_t)r * ldo + c4 * 4) = acc;
}

__global__ __launch_bounds__(256) void reduce_bf16_kernel(
    const float* __restrict__ pbuf, const float* __restrict__ bias,
    unsigned short* __restrict__ out, int ldo, int rowlen4, int nz, size_t zstride, int total4)
{
  int idx = blockIdx.x * 256 + threadIdx.x;
  if (idx >= total4) return;
  int r = idx / rowlen4, c4 = idx % rowlen4;
  fl4 acc = *(const fl4*)(bias + c4 * 4);
  for (int z = 0; z < nz; ++z)
    acc += *(const fl4*)(pbuf + z * zstride + (size_t)idx * 4);
  us4 u = { f2bf(acc[0]), f2bf(acc[1]), f2bf(acc[2]), f2bf(acc[3]) };
  *(us4*)(out + (size_t)r * ldo + c4 * 4) = u;
}

// ---------------- rope tables + table-based rope ------------------------------
__global__ __launch_bounds__(256) void rope_table_kernel(float* __restrict__ ctab,
                                                         float* __restrict__ stab) {
  int idx = blockIdx.x * 256 + threadIdx.x;   // S_LEN*32 entries
  if (idx >= S_LEN * 32) return;
  int j = idx & 31, s = idx >> 5;
  float invf = expf(-0.28782313662425574f * (float)j);   // 10000^(-j/32)
  float ang = (float)s * invf;
  ctab[idx] = cosf(ang);
  stab[idx] = sinf(ang);
}

__global__ void rope_bf16_kernel(unsigned short* __restrict__ x, int nh, int lda, int total,
                                 const float* __restrict__ ctab,
                                 const float* __restrict__ stab) {
  int idx = blockIdx.x * 256 + threadIdx.x;
  if (idx >= total) return;
  int j = idx & 31;
  int rest = idx >> 5;
  int hh = rest % nh;
  int s = rest / nh;
  float c = ctab[s * 32 + j], sn = stab[s * 32 + j];
  size_t base = (size_t)s * lda + hh * 64;
  float x1 = bf2f(x[base + j]), x2 = bf2f(x[base + j + 32]);
  x[base + j]      = f2bf(x1 * c - x2 * sn);
  x[base + j + 32] = f2bf(x2 * c + x1 * sn);
}

// ---------------- V transpose -------------------------------------------------
__global__ __launch_bounds__(256) void vtrans_kernel(
    const unsigned short* __restrict__ kvb, unsigned short* __restrict__ vt) {
  __shared__ unsigned short tl[64][72];
  const int s0 = blockIdx.x * 64;
  const int c0 = blockIdx.y * 64;
  const int t = threadIdx.x;
  const int rr = t >> 3, cc = (t & 7) * 8;
  const int hbase = (c0 >> 7) * 256 + 128 + (c0 & 127);
#pragma unroll
  for (int i = 0; i < 2; ++i) {
    int r = rr + i * 32;
    *reinterpret_cast<bf16x8*>(&tl[r][cc]) =
        *reinterpret_cast<const bf16x8*>(kvb + (size_t)(s0 + r) * 32768 + hbase + cc);
  }
  __syncthreads();
#pragma unroll
  for (int i = 0; i < 2; ++i) {
    int vc = rr + i * 32;
    unsigned short tmp[8];
#pragma unroll
    for (int j = 0; j < 8; ++j) tmp[j] = tl[cc + j][vc];
    *reinterpret_cast<bf16x8*>(&vt[(size_t)(c0 + vc) * 1024 + s0 + cc]) =
        *reinterpret_cast<bf16x8*>(tmp);
  }
}

// ---------------- flash attention ---------------------------------------------
__global__ __launch_bounds__(256) void mla_attn_kernel(
    const unsigned short* __restrict__ qcat,
    const unsigned short* __restrict__ kvb,
    const unsigned short* __restrict__ kr,
    const unsigned short* __restrict__ vt,
    unsigned short* __restrict__ obuf)
{
  __shared__ unsigned short Klds[64][200];
  __shared__ unsigned short Vlds[128][72];
  __shared__ unsigned short Plds[4][16][72];

  const int t = threadIdx.x;
  const int l = t & 63, w = t >> 6;
  const int r15 = l & 15, g = l >> 4;
  const int bid = blockIdx.x;
  const int orig = (bid & 7) * 256 + (bid >> 3);   // 2048 % 8 == 0: bijective
  const int h = orig >> 4;
  const int q0 = (orig & 15) * 64;

  bf16x8 qf[6];
  const unsigned short* qrow = qcat + (size_t)(q0 + w * 16 + r15) * 24576;
#pragma unroll
  for (int kk = 0; kk < 4; ++kk)
    qf[kk] = *reinterpret_cast<const bf16x8*>(qrow + h * 128 + kk * 32 + 8 * g);
#pragma unroll
  for (int kk = 4; kk < 6; ++kk)
    qf[kk] = *reinterpret_cast<const bf16x8*>(qrow + 16384 + h * 64 + (kk - 4) * 32 + 8 * g);

  bf16x8 kreg[6], vreg[4];
  auto loadKV = [&](int kk0) {
#pragma unroll
    for (int i = 0; i < 6; ++i) {
      int c = t + 256 * i, row = c / 24, cb = c % 24;
      const unsigned short* src = (cb < 16)
          ? kvb + (size_t)(kk0 + row) * 32768 + h * 256 + cb * 8
          : kr + (size_t)(kk0 + row) * 2112 + (cb - 16) * 8;
      kreg[i] = *reinterpret_cast<const bf16x8*>(src);
    }
#pragma unroll
    for (int i = 0; i < 4; ++i) {
      int c = t + 256 * i, d = c >> 3, kb = c & 7;
      vreg[i] = *reinterpret_cast<const bf16x8*>(vt + ((size_t)h * 128 + d) * 1024 + kk0 + kb * 8);
    }
  };

  float m_r[4], l_r[4];
  f32x4 oacc[8];
#pragma unroll
  for (int r = 0; r < 4; ++r) { m_r[r] = -1e30f; l_r[r] = 0.f; }
#pragma unroll
  for (int d = 0; d < 8; ++d) oacc[d] = (f32x4){0.f, 0.f, 0.f, 0.f};

  loadKV(0);

  for (int kt = 0; kt < 16; ++kt) {
    __syncthreads();
#pragma unroll
    for (int i = 0; i < 6; ++i) {
      int c = t + 256 * i, row = c / 24, cb = c % 24;
      *reinterpret_cast<bf16x8*>(&Klds[row][cb * 8]) = kreg[i];
    }
#pragma unroll
    for (int i = 0; i < 4; ++i) {
      int c = t + 256 * i, d = c >> 3, kb = c & 7;
      *reinterpret_cast<bf16x8*>(&Vlds[d][kb * 8]) = vreg[i];
    }
    __syncthreads();
    if (kt < 15) loadKV((kt + 1) * 64);   // T14: loads land during compute

    // S = Q K^T
    f32x4 sacc[4];
#pragma unroll
    for (int nt = 0; nt < 4; ++nt) sacc[nt] = (f32x4){0.f, 0.f, 0.f, 0.f};
    __builtin_amdgcn_s_setprio(1);
#pragma unroll
    for (int nt = 0; nt < 4; ++nt)
#pragma unroll
      for (int kk = 0; kk < 6; ++kk) {
        bf16x8 b = *reinterpret_cast<const bf16x8*>(&Klds[nt * 16 + r15][kk * 32 + 8 * g]);
        sacc[nt] = __builtin_amdgcn_mfma_f32_16x16x32_bf16(qf[kk], b, sacc[nt], 0, 0, 0);
      }
    __builtin_amdgcn_s_setprio(0);

    // online softmax
    float sc[4], rsum[4];
#pragma unroll
    for (int r = 0; r < 4; ++r) {
      float mx = fmaxf(fmaxf(sacc[0][r], sacc[1][r]), fmaxf(sacc[2][r], sacc[3][r]));
      mx = fmaxf(mx, __shfl_xor(mx, 1));
      mx = fmaxf(mx, __shfl_xor(mx, 2));
      mx = fmaxf(mx, __shfl_xor(mx, 4));
      mx = fmaxf(mx, __shfl_xor(mx, 8));
      float mn = fmaxf(m_r[r], mx);
      sc[r] = __expf(m_r[r] - mn);
      m_r[r] = mn;
      rsum[r] = 0.f;
    }
#pragma unroll
    for (int nt = 0; nt < 4; ++nt)
#pragma unroll
      for (int r = 0; r < 4; ++r) {
        float p = __expf(sacc[nt][r] - m_r[r]);
        rsum[r] += p;
        Plds[w][g * 4 + r][nt * 16 + r15] = f2bf(p);
      }
#pragma unroll
    for (int r = 0; r < 4; ++r) {
      float s = rsum[r];
      s += __shfl_xor(s, 1);
      s += __shfl_xor(s, 2);
      s += __shfl_xor(s, 4);
      s += __shfl_xor(s, 8);
      l_r[r] = l_r[r] * sc[r] + s;
    }
#pragma unroll
    for (int d = 0; d < 8; ++d)
#pragma unroll
      for (int r = 0; r < 4; ++r) oacc[d][r] *= sc[r];

    // O += P V
    bf16x8 pa0 = *reinterpret_cast<const bf16x8*>(&Plds[w][r15][8 * g]);
    bf16x8 pa1 = *reinterpret_cast<const bf16x8*>(&Plds[w][r15][32 + 8 * g]);
    __builtin_amdgcn_s_setprio(1);
#pragma unroll
    for (int dt = 0; dt < 8; ++dt) {
      bf16x8 v0 = *reinterpret_cast<const bf16x8*>(&Vlds[dt * 16 + r15][8 * g]);
      bf16x8 v1 = *reinterpret_cast<const bf16x8*>(&Vlds[dt * 16 + r15][32 + 8 * g]);
      oacc[dt] = __builtin_amdgcn_mfma_f32_16x16x32_bf16(pa0, v0, oacc[dt], 0, 0, 0);
      oacc[dt] = __builtin_amdgcn_mfma_f32_16x16x32_bf16(pa1, v1, oacc[dt], 0, 0, 0);
    }
    __builtin_amdgcn_s_setprio(0);
  }

#pragma unroll
  for (int dt = 0; dt < 8; ++dt)
#pragma unroll
    for (int r = 0; r < 4; ++r) {
      int row = q0 + w * 16 + g * 4 + r;
      int col = h * DH + dt * 16 + r15;
      obuf[(size_t)row * 16384 + col] = f2bf(oacc[dt][r] / l_r[r]);
    }
}

// ------------------------------------------------------------------------------
extern "C" void kernel_launch(void* const* d_in, const int* in_sizes, int n_in,
                              void* d_out, int out_size, void* d_ws, size_t ws_size,
                              hipStream_t stream) {
  const float* h    = (const float*)d_in[0];
  const float* Wdq  = (const float*)d_in[1];
  const float* bdq  = (const float*)d_in[2];
  const float* Wdkv = (const float*)d_in[3];
  const float* bdkv = (const float*)d_in[4];
  const float* Wuq  = (const float*)d_in[5];
  const float* buq  = (const float*)d_in[6];
  const float* Wukv = (const float*)d_in[7];
  const float* bukv = (const float*)d_in[8];
  const float* Wrq  = (const float*)d_in[9];
  const float* brq  = (const float*)d_in[10];
  const float* Wrk  = (const float*)d_in[11];
  const float* brk  = (const float*)d_in[12];
  const float* Wo   = (const float*)d_in[13];
  const float* bo   = (const float*)d_in[14];
  float* out = (float*)d_out;

  char* ws = (char*)d_ws;
  size_t off = 0;
  auto alloc = [&](size_t bytes) {
    char* p = ws + off;
    off += (bytes + 255) & ~(size_t)255;
    return p;
  };
  unsigned short* hb    = (unsigned short*)alloc((size_t)1024 * 7168 * 2);
  unsigned short* W1cat = (unsigned short*)alloc((size_t)2176 * 7168 * 2);
  float*          b1cat = (float*)alloc(2176 * 4);
  unsigned short* ccat  = (unsigned short*)alloc((size_t)1024 * 2112 * 2);
  float*          b2cat = (float*)alloc(24576 * 4);
  unsigned short* qcat  = (unsigned short*)alloc((size_t)1024 * 24576 * 2);
  unsigned short* kvbb  = (unsigned short*)alloc((size_t)1024 * 32768 * 2);
  unsigned short* vt    = (unsigned short*)alloc((size_t)16384 * 1024 * 2);
  unsigned short* obuf  = (unsigned short*)alloc((size_t)1024 * 16384 * 2);
  float*          ctab  = (float*)alloc((size_t)S_LEN * 32 * 4);
  float*          stab  = (float*)alloc((size_t)S_LEN * 32 * 4);
  // G1 split-K partials alias not-yet-written qcat (34.6 MB < 50.3 MB)
  float* pbufG1 = (float*)qcat;
  // G4 split-K partials (4 x 1024 x 7168 fp32 = 117.44 MB) alias qcat+kvbb
  // (exactly 117.44 MB), both dead after attention; obuf untouched.
  float* pbufG4 = (float*)qcat;

  auto cvt = [&](const float* in, unsigned short* outp, size_t n) {
    int n8 = (int)(n / 8);
    int blocks = (n8 + 255) / 256;
    if (blocks > 2048) blocks = 2048;
    cvt_bf16_kernel<<<blocks, 256, 0, stream>>>(in, outp, n8);
  };

  // --- conversions kept only for h and the small concatenated W1 ---
  cvt(h,    hb,    (size_t)1024 * 7168);
  cvt(Wdq,  W1cat, (size_t)1536 * 7168);
  cvt(Wdkv, W1cat + (size_t)1536 * 7168, (size_t)512 * 7168);
  cvt(Wrk,  W1cat + (size_t)2048 * 7168, (size_t)64 * 7168);
  hipMemsetAsync(W1cat + (size_t)2112 * 7168, 0, (size_t)64 * 7168 * 2, stream);
  hipMemcpyAsync(b1cat,        bdq,  1536 * 4, hipMemcpyDeviceToDevice, stream);
  hipMemcpyAsync(b1cat + 1536, bdkv, 512 * 4,  hipMemcpyDeviceToDevice, stream);
  hipMemcpyAsync(b1cat + 2048, brk,  64 * 4,   hipMemcpyDeviceToDevice, stream);
  hipMemsetAsync(b1cat + 2112, 0, 64 * 4, stream);
  hipMemcpyAsync(b2cat,         buq, 16384 * 4, hipMemcpyDeviceToDevice, stream);
  hipMemcpyAsync(b2cat + 16384, brq, 8192 * 4,  hipMemcpyDeviceToDevice, stream);
  rope_table_kernel<<<(S_LEN * 32 + 255) / 256, 256, 0, stream>>>(ctab, stab);

  const float scale = 0.07216878364870323f;   // 1/sqrt(192)
  const int BIGN = 1 << 30;
  dim3 blk(256);

  // G1 (split-K=4, bf16 W): partials = h @ W1cat^T.  grid.x padded 17->24 (XCD colocation)
  gemm_k<2, 0><<<dim3(24, 8, 4), blk, 0, stream>>>(
      hb, 7168, W1cat, nullptr, nullptr, BIGN, 7168, nullptr,
      pbufG1, 2112, (size_t)1024 * 2112, 2112, 1792, 1.0f);
  reduce_bf16_kernel<<<2112, blk, 0, stream>>>(pbufG1, b1cat, ccat, 2112, 528, 4,
                                               (size_t)1024 * 2112, 1024 * 2112 / 4);
  rope_bf16_kernel<<<(1024 * 32 + 255) / 256, blk, 0, stream>>>(ccat + 2048, 1, 2112, 1024 * 32, ctab, stab);

  // G2 (fp32 W direct): [q_c | q_r] = (c_q @ [Wuq;Wrq]^T + b2cat) * scale
  gemm_k<1, 1><<<dim3(192, 8, 1), blk, 0, stream>>>(
      ccat, 2112, nullptr, Wuq, Wrq, 16384, 1536, b2cat,
      qcat, 24576, 0, 24576, 1536, scale);
  rope_bf16_kernel<<<(1024 * 128 * 32 + 255) / 256, blk, 0, stream>>>(qcat + 16384, 128, 24576, 1024 * 128 * 32, ctab, stab);

  // G3 (fp32 W direct): kv = c_kv @ Wukv^T + bukv
  gemm_k<1, 1><<<dim3(256, 8, 1), blk, 0, stream>>>(
      ccat + 1536, 2112, nullptr, Wukv, Wukv, BIGN, 512, bukv,
      kvbb, 32768, 0, 32768, 512, 1.0f);
  vtrans_kernel<<<dim3(16, 256), blk, 0, stream>>>(kvbb, vt);
  mla_attn_kernel<<<dim3(2048), blk, 0, stream>>>(qcat, kvbb, ccat + 2048, vt, obuf);

  // G4 (single launch, split-K=4, fp32 W direct): out = obuf @ Wo^T + bo
  // grid (56, 8, 4): 56 % 8 == 0 keeps the 8 m-blocks of an n-tile on one XCD.
  gemm_k<2, 1><<<dim3(56, 8, 4), blk, 0, stream>>>(
      obuf, 16384, nullptr, Wo, Wo, BIGN, 16384, nullptr,
      pbufG4, 7168, (size_t)1024 * 7168, 7168, 4096, 1.0f);
  reduce_f32_kernel<<<7168, blk, 0, stream>>>(pbufG4, bo, out,
                                              7168, 1792, 4, (size_t)1024 * 7168, 1024 * 7168 / 4);
}